// Round 12
// baseline (291.589 us; speedup 1.0000x reference)
//
#include <hip/hip_runtime.h>

#define EPS_ 1e-5f

typedef float f32x4 __attribute__((ext_vector_type(4)));
typedef float f32x16 __attribute__((ext_vector_type(16)));
typedef short s16x8 __attribute__((ext_vector_type(8)));

static __device__ __forceinline__ short f2bf(float f) {
    unsigned u = __float_as_uint(f);
    unsigned r = (u + 0x7FFFu + ((u >> 16) & 1u)) >> 16;
    return (short)r;
}
static __device__ __forceinline__ float bf2f(short s) {
    return __uint_as_float(((unsigned)(unsigned short)s) << 16);
}

// async global->LDS, 16B per lane, wave-uniform LDS base
static __device__ __forceinline__ void gload16(const short* g, short* l) {
    __builtin_amdgcn_global_load_lds(
        (const __attribute__((address_space(1))) unsigned int*)g,
        (__attribute__((address_space(3))) unsigned int*)l, 16, 0, 0);
}

// ---------------------------------------------------------------------------
// Kernel 0: convert weight stacks to bf16 once.
// ---------------------------------------------------------------------------
__global__ __launch_bounds__(256) void prep_kernel(
    const float* __restrict__ Wq, const float* __restrict__ Wk,
    const float* __restrict__ Wv, const float* __restrict__ Wp,
    short* __restrict__ Wbf, short* __restrict__ Wpbf)
{
    int i = blockIdx.x * 256 + threadIdx.x;
    if (i < 6144) {
        float v = (i < 1024) ? Wq[i] : (i < 2048 ? Wk[i - 1024] : Wv[i - 2048]);
        Wbf[i] = f2bf(v);
    } else if (i < 6144 + 4096) {
        Wpbf[i - 6144] = f2bf(Wp[i - 6144]);
    }
}

// ---------------------------------------------------------------------------
// Kernel 1: QKV projection via MFMA + PReLU + LN(chan,freq), write bf16.
// ---------------------------------------------------------------------------
__global__ __launch_bounds__(256) void qkv_kernel(
    const float* __restrict__ x, const short* __restrict__ Wbf,
    const float* __restrict__ bq, const float* __restrict__ aq,
    const float* __restrict__ gq, const float* __restrict__ betq,
    const float* __restrict__ bk, const float* __restrict__ ak,
    const float* __restrict__ gk, const float* __restrict__ betk,
    const float* __restrict__ bv, const float* __restrict__ av,
    const float* __restrict__ gv, const float* __restrict__ betv,
    short* __restrict__ Qo, short* __restrict__ Ko, short* __restrict__ Vo)
{
    const int t = blockIdx.x;
    const int b = blockIdx.y;
    const int tid = threadIdx.x;
    const int wid = tid >> 6, lane = tid & 63;
    const int g = lane >> 4, c16 = lane & 15;
    const int f_ = tid & 63, cg = tid >> 6;

    __shared__ __align__(16) short wlds[96 * 64];
    __shared__ __align__(16) short xs[64 * 64];
    __shared__ float zs[96 * 64];
    __shared__ float stats[12][2];
    __shared__ float bias_l[96], alpha_l[96];

#pragma unroll
    for (int j = 0; j < 3; ++j) {
        int i8 = tid + 256 * j;
        int row = i8 >> 3, cb = i8 & 7;
        s16x8 v = *(const s16x8*)(Wbf + i8 * 8);
        *(s16x8*)&wlds[row * 64 + ((cb ^ (row & 7)) * 8)] = v;
    }
    if (tid < 96) {
        int row = tid; float bias, al;
        if (row < 16)      { bias = bq[row];      al = aq[row >> 2]; }
        else if (row < 32) { bias = bk[row - 16]; al = ak[(row - 16) >> 2]; }
        else               { bias = bv[row - 32]; al = av[(row - 32) >> 4]; }
        bias_l[row] = bias; alpha_l[row] = al;
    }
#pragma unroll
    for (int it = 0; it < 2; ++it) {
        int cb = cg + 4 * it, c0 = cb * 8;
        s16x8 v;
#pragma unroll
        for (int i = 0; i < 8; ++i)
            v[i] = f2bf(x[(((size_t)b * 64 + c0 + i) * 2048 + t) * 64 + f_]);
        *(s16x8*)&xs[f_ * 64 + ((cb ^ (f_ & 7)) * 8)] = v;
    }
    __syncthreads();

    const int f0 = wid * 16;
    s16x8 bfr[2];
#pragma unroll
    for (int kk = 0; kk < 2; ++kk)
        bfr[kk] = *(const s16x8*)&xs[(f0 + c16) * 64 + (((kk * 4 + g) ^ (c16 & 7)) * 8)];

    f32x4 acc[6];
#pragma unroll
    for (int rt = 0; rt < 6; ++rt) {
#pragma unroll
        for (int r = 0; r < 4; ++r) acc[rt][r] = 0.f;
#pragma unroll
        for (int kk = 0; kk < 2; ++kk) {
            s16x8 a = *(const s16x8*)&wlds[(rt * 16 + c16) * 64 + (((kk * 4 + g) ^ (c16 & 7)) * 8)];
            acc[rt] = __builtin_amdgcn_mfma_f32_16x16x32_bf16(a, bfr[kk], acc[rt], 0, 0, 0);
        }
    }

#pragma unroll
    for (int rt = 0; rt < 6; ++rt)
#pragma unroll
        for (int r = 0; r < 4; ++r) {
            int row = rt * 16 + g * 4 + r;
            float z = acc[rt][r] + bias_l[row];
            z = z >= 0.f ? z : alpha_l[row] * z;
            zs[row * 64 + f0 + c16] = z;
        }
    __syncthreads();

#pragma unroll
    for (int gi = 0; gi < 3; ++gi) {
        int grp = wid * 3 + gi;
        int base_row, n;
        if (grp < 4)      { base_row = grp * 4;             n = 256; }
        else if (grp < 8) { base_row = 16 + (grp - 4) * 4;  n = 256; }
        else              { base_row = 32 + (grp - 8) * 16; n = 1024; }
        int cnt = n >> 6;
        float s = 0.f, ss = 0.f;
        for (int i = 0; i < cnt; ++i) {
            float v = zs[(base_row + i) * 64 + lane];
            s += v; ss += v * v;
        }
#pragma unroll
        for (int msk = 32; msk >= 1; msk >>= 1) {
            s  += __shfl_xor(s, msk);
            ss += __shfl_xor(ss, msk);
        }
        if (lane == 0) {
            float mean = s / n;
            float var = ss / n - mean * mean;
            stats[grp][0] = mean;
            stats[grp][1] = rsqrtf(var + EPS_);
        }
    }
    __syncthreads();

#pragma unroll
    for (int j = 0; j < 24; ++j) {
        int row = cg + 4 * j;
        float zv = zs[row * 64 + f_];
        if (row < 16) {
            int grp = row >> 2;
            float val = (zv - stats[grp][0]) * stats[grp][1];
            val = val * gq[row * 64 + f_] + betq[row * 64 + f_];
            int h = row >> 2, o = row & 3;
            Qo[(((size_t)(h * 2 + b)) * 2048 + t) * 256 + o * 64 + f_] = f2bf(val);
        } else if (row < 32) {
            int rr = row - 16, grp = 4 + (rr >> 2);
            float val = (zv - stats[grp][0]) * stats[grp][1];
            val = val * gk[rr * 64 + f_] + betk[rr * 64 + f_];
            int h = rr >> 2, o = rr & 3;
            Ko[(((size_t)(h * 2 + b)) * 2048 + t) * 256 + o * 64 + f_] = f2bf(val);
        } else {
            int rr = row - 32, grp = 8 + (rr >> 4);
            float val = (zv - stats[grp][0]) * stats[grp][1];
            val = val * gv[rr * 64 + f_] + betv[rr * 64 + f_];
            int h = rr >> 4, ov = rr & 15;
            Vo[(((size_t)(h * 2 + b)) * 2048 + t) * 1024 + ov * 64 + f_] = f2bf(val);
        }
    }
}

// ---------------------------------------------------------------------------
// Kernel 2: V row-major [hb][t][d] -> V^T [hb][d][pi(t)].
// pi relabels keys within each 32-aligned t-block so the in-register P from
// the 32x32 swapped QK^T feeds PV's A-operand with zero cross-lane movement:
// storage position c (c4..c0) holds original key 8*(2*c4 + c2) + 4*c3 + c1c0.
// ---------------------------------------------------------------------------
__global__ __launch_bounds__(256) void vtrans_kernel(
    const short* __restrict__ Vrm, short* __restrict__ Vt)
{
    const int t0 = blockIdx.x * 64;
    const int d0 = blockIdx.y * 64;
    const int hb = blockIdx.z;
    const int tid = threadIdx.x;
    __shared__ __align__(16) short tile[64 * 72];

#pragma unroll
    for (int k = 0; k < 2; ++k) {
        int q = tid + 256 * k;
        int row = q >> 3, slot = q & 7;
        s16x8 v = *(const s16x8*)(Vrm + ((size_t)hb * 2048 + t0 + row) * 1024 + d0 + slot * 8);
        *(s16x8*)&tile[row * 72 + slot * 8] = v;
    }
    __syncthreads();
#pragma unroll
    for (int k = 0; k < 2; ++k) {
        int q = tid + 256 * k;
        int drow = q >> 3, tslot = q & 7;
        s16x8 v;
#pragma unroll
        for (int i = 0; i < 8; ++i) {
            int c = tslot * 8 + i;
            int cl = c & 31;
            int step = (cl >> 4) & 1, hi2 = (cl >> 3) & 1, e2 = (cl >> 2) & 1, e1 = cl & 3;
            int src = (c & 32) + 8 * (2 * step + e2) + 4 * hi2 + e1;
            v[i] = tile[src * 72 + drow];
        }
        *(s16x8*)(Vt + ((size_t)hb * 1024 + d0 + drow) * 2048 + t0 + tslot * 8) = v;
    }
}

// ---------------------------------------------------------------------------
// Kernel 3: flash attention, 32x32x16 MFMA (2x FLOP per LDS byte).
// Grid (8 hb, 16 qt, 2 dh) = 256 blocks, 512 thr (8 waves).
// Wave wid: qg = wid&3 owns q-rows [t0+qg*32, +32); ds2 = wid>>2 owns
// d-slice [dh*512 + ds2*256, +256). KBLK=32, 64 k-tiles.
// Swapped QK^T (A=K, B=Q, 32x32x16, dual accumulator): lane holds
// S^T[16 keys][q = lane&31]; softmax in-register (16 exp + 1 shfl);
// pi makes PV A-frags = sf[0..7], sf[8..15] verbatim.
// K (32x256, 16KB) and V (512x32, 32KB) DMA'd to LDS, double-buffered;
// between barriers only {ds_read, MFMA, VALU}. 1 barrier/tile.
// Per wave per tile: 16+16 MFMA(32x32) + 32 ds_read_b128 (was 48+48).
// ---------------------------------------------------------------------------
__global__ __launch_bounds__(512, 2) void attn_kernel(
    const short* __restrict__ Qg, const short* __restrict__ Kg,
    const short* __restrict__ Vt, short* __restrict__ Ob)
{
    const int hb = blockIdx.x;
    const int qt = blockIdx.y;     // 0..15
    const int dh = blockIdx.z;     // 0..1
    const int t0 = qt * 128;
    const int tid = threadIdx.x;
    const int lane = tid & 63;
    const int wid = tid >> 6;
    const int qg = wid & 3;        // q-group (32 rows)
    const int ds2 = wid >> 2;      // d-slice (256 of the block's 512)
    const int q5 = lane & 31, hi = lane >> 5;

    __shared__ __align__(16) short k_lds[2][32 * 256];   // 2x16 KB
    __shared__ __align__(16) short v_lds[2][512 * 32];   // 2x32 KB

    const size_t kgbase = (size_t)hb * 2048 * 256;
    const size_t vgbase = ((size_t)hb * 1024 + dh * 512) * 2048;

    // Q B-fragments: lane holds Q[kdim = kf*16 + hi*8 + e][q = q5]
    const size_t qrow = (size_t)hb * 2048 + t0 + qg * 32 + q5;
    s16x8 qf[16];
#pragma unroll
    for (int kf = 0; kf < 16; ++kf)
        qf[kf] = *(const s16x8*)(Qg + qrow * 256 + kf * 16 + hi * 8);

    f32x16 oacc[8];                // [dt]: O[q=(r&3)+8*(r>>2)+4*hi][d=dt*32+q5]
#pragma unroll
    for (int i = 0; i < 8; ++i)
#pragma unroll
        for (int r = 0; r < 16; ++r) oacc[i][r] = 0.f;

    float l_r = 0.f;               // softmax denom for q = q5

    // DMA-stage K (32x256) and V (512x32) for tile kt: linear LDS dest,
    // inverse-swizzled global source.
#define STAGE(buf, kt) do {                                                    \
    _Pragma("unroll")                                                          \
    for (int j_ = 0; j_ < 2; ++j_) {                                           \
        int c_ = tid + 512 * j_;                                               \
        int row_ = c_ >> 5, sp_ = c_ & 31;                                     \
        int sl_ = sp_ ^ (row_ & 7);                                            \
        gload16(Kg + kgbase + (size_t)((kt) * 32 + row_) * 256 + sl_ * 8,      \
                &k_lds[buf][c_ * 8]);                                          \
    }                                                                          \
    _Pragma("unroll")                                                          \
    for (int j_ = 0; j_ < 4; ++j_) {                                           \
        int c_ = tid + 512 * j_;                                               \
        int row_ = c_ >> 2, sp_ = c_ & 3;                                      \
        int sl_ = sp_ ^ ((row_ >> 1) & 3);                                     \
        gload16(Vt + vgbase + (size_t)row_ * 2048 + (kt) * 32 + sl_ * 8,       \
                &v_lds[buf][c_ * 8]);                                          \
    }                                                                          \
} while (0)

    // prologue
    STAGE(0, 0);
    __syncthreads();

    for (int t = 0; t < 64; ++t) {
        const int buf = t & 1;

        if (t < 63) STAGE(buf ^ 1, t + 1);

        // QK^T swapped, dual accumulator (halved dep chain):
        // sf[r] = S^T[key = (r&3)+8*(r>>2)+4*hi][q = q5]
        f32x16 sf0, sf1;
#pragma unroll
        for (int r = 0; r < 16; ++r) { sf0[r] = 0.f; sf1[r] = 0.f; }
        __builtin_amdgcn_s_setprio(1);
#pragma unroll
        for (int kf = 0; kf < 8; ++kf) {
            s16x8 ka0 = *(const s16x8*)&k_lds[buf]
                [q5 * 256 + ((((2 * kf) * 2 + hi) ^ (q5 & 7)) * 8)];
            sf0 = __builtin_amdgcn_mfma_f32_32x32x16_bf16(ka0, qf[2 * kf], sf0, 0, 0, 0);
            s16x8 ka1 = *(const s16x8*)&k_lds[buf]
                [q5 * 256 + ((((2 * kf + 1) * 2 + hi) ^ (q5 & 7)) * 8)];
            sf1 = __builtin_amdgcn_mfma_f32_32x32x16_bf16(ka1, qf[2 * kf + 1], sf1, 0, 0, 0);
        }
        __builtin_amdgcn_s_setprio(0);

        // softmax in-register (no max: Q,K LayerNorm'd): 16 exp + 1 shfl
        float p16[16];
        float rs = 0.f;
#pragma unroll
        for (int r = 0; r < 16; ++r) {
            float p = __expf((sf0[r] + sf1[r]) * 0.0625f);
            p16[r] = p;
            rs += p;
        }
        rs += __shfl_xor(rs, 32);
        l_r += rs;

        // pack P -> PV A-fragments (identity thanks to pi): pa0 = p16[0..7]
        s16x8 pa0, pa1;
#pragma unroll
        for (int e = 0; e < 8; ++e) {
            pa0[e] = f2bf(p16[e]);
            pa1[e] = f2bf(p16[8 + e]);
        }

        // PV: 8 d-tiles x 2 k-steps (16 MFMA, independent accumulators)
        __builtin_amdgcn_s_setprio(1);
#pragma unroll
        for (int dt = 0; dt < 8; ++dt) {
            int rowv = ds2 * 256 + dt * 32 + q5;
            s16x8 vb0 = *(const s16x8*)&v_lds[buf]
                [rowv * 32 + (((0 * 2 + hi) ^ ((rowv >> 1) & 3)) * 8)];
            oacc[dt] = __builtin_amdgcn_mfma_f32_32x32x16_bf16(pa0, vb0, oacc[dt], 0, 0, 0);
            s16x8 vb1 = *(const s16x8*)&v_lds[buf]
                [rowv * 32 + (((1 * 2 + hi) ^ ((rowv >> 1) & 3)) * 8)];
            oacc[dt] = __builtin_amdgcn_mfma_f32_32x32x16_bf16(pa1, vb1, oacc[dt], 0, 0, 0);
        }
        __builtin_amdgcn_s_setprio(0);

        if (t < 63) __syncthreads();
    }

#undef STAGE

    // epilogue: li[r] = 1/l for q = (r&3)+8*(r>>2)+4*hi (lives in lane q)
    float li[16];
#pragma unroll
    for (int r = 0; r < 16; ++r) {
        int q_r = (r & 3) + 8 * (r >> 2) + 4 * hi;
        li[r] = 1.f / __shfl(l_r, q_r);
    }

    const int h = hb >> 1, b = hb & 1;
#pragma unroll
    for (int dt = 0; dt < 8; ++dt) {
        int vcol = dh * 512 + ds2 * 256 + dt * 32 + q5;
        int cout = h * 16 + (vcol >> 6), ff = vcol & 63;
#pragma unroll
        for (int r = 0; r < 16; ++r) {
            int q_r = (r & 3) + 8 * (r >> 2) + 4 * hi;
            int trow = t0 + qg * 32 + q_r;
            Ob[(((size_t)b * 64 + cout) * 2048 + trow) * 64 + ff] =
                f2bf(oacc[dt][r] * li[r]);
        }
    }
}

// ---------------------------------------------------------------------------
// Kernel 4: output projection via MFMA + PReLU + LN(C,F) + residual
// ---------------------------------------------------------------------------
__global__ __launch_bounds__(256) void oproj_kernel(
    const short* __restrict__ Ob, const float* __restrict__ x,
    const short* __restrict__ Wpbf,
    const float* __restrict__ bp, const float* __restrict__ ap,
    const float* __restrict__ gp, const float* __restrict__ betp,
    float* __restrict__ out)
{
    const int t = blockIdx.x;
    const int b = blockIdx.y;
    const int tid = threadIdx.x;
    const int wid = tid >> 6, lane = tid & 63;
    const int g = lane >> 4, c16 = lane & 15;
    const int f_ = tid & 63, cg = tid >> 6;

    __shared__ __align__(16) short wp[64 * 64];
    __shared__ __align__(16) short os[64 * 64];
    __shared__ float zs[64 * 64];
    __shared__ float red[4][2];

#pragma unroll
    for (int j = 0; j < 2; ++j) {
        int i8 = tid + 256 * j;
        int row = i8 >> 3, cb = i8 & 7;
        s16x8 v = *(const s16x8*)(Wpbf + i8 * 8);
        *(s16x8*)&wp[row * 64 + ((cb ^ (row & 7)) * 8)] = v;
    }
#pragma unroll
    for (int it = 0; it < 2; ++it) {
        int cb = cg + 4 * it, c0 = cb * 8;
        s16x8 v;
#pragma unroll
        for (int i = 0; i < 8; ++i)
            v[i] = Ob[(((size_t)b * 64 + c0 + i) * 2048 + t) * 64 + f_];
        *(s16x8*)&os[f_ * 64 + ((cb ^ (f_ & 7)) * 8)] = v;
    }
    __syncthreads();

    const int f0 = wid * 16;
    s16x8 bfr[2];
#pragma unroll
    for (int kk = 0; kk < 2; ++kk)
        bfr[kk] = *(const s16x8*)&os[(f0 + c16) * 64 + (((kk * 4 + g) ^ (c16 & 7)) * 8)];

    const float ap0 = ap[0];
    f32x4 acc[4];
#pragma unroll
    for (int rt = 0; rt < 4; ++rt) {
#pragma unroll
        for (int r = 0; r < 4; ++r) acc[rt][r] = 0.f;
#pragma unroll
        for (int kk = 0; kk < 2; ++kk) {
            s16x8 a = *(const s16x8*)&wp[(rt * 16 + c16) * 64 + (((kk * 4 + g) ^ (c16 & 7)) * 8)];
            acc[rt] = __builtin_amdgcn_mfma_f32_16x16x32_bf16(a, bfr[kk], acc[rt], 0, 0, 0);
        }
    }

#pragma unroll
    for (int rt = 0; rt < 4; ++rt)
#pragma unroll
        for (int r = 0; r < 4; ++r) {
            int row = rt * 16 + g * 4 + r;
            float z = acc[rt][r] + bp[row];
            z = z >= 0.f ? z : ap0 * z;
            zs[row * 64 + f0 + c16] = z;
        }
    __syncthreads();

    float s = 0.f, ss = 0.f;
#pragma unroll
    for (int j = 0; j < 16; ++j) {
        float v = zs[(cg + 4 * j) * 64 + f_];
        s += v; ss += v * v;
    }
#pragma unroll
    for (int msk = 32; msk >= 1; msk >>= 1) {
        s  += __shfl_xor(s, msk);
        ss += __shfl_xor(ss, msk);
    }
    if (lane == 0) { red[wid][0] = s; red[wid][1] = ss; }
    __syncthreads();
    float ts  = red[0][0] + red[1][0] + red[2][0] + red[3][0];
    float tss = red[0][1] + red[1][1] + red[2][1] + red[3][1];
    float mean = ts * (1.f / 4096.f);
    float rstd = rsqrtf(tss * (1.f / 4096.f) - mean * mean + EPS_);

#pragma unroll
    for (int j = 0; j < 16; ++j) {
        int row = cg + 4 * j;
        size_t idx = (((size_t)b * 64 + row) * 2048 + t) * 64 + f_;
        out[idx] = (zs[row * 64 + f_] - mean) * rstd * gp[row * 64 + f_]
                 + betp[row * 64 + f_] + x[idx];
    }
}

// ---------------------------------------------------------------------------
extern "C" void kernel_launch(void* const* d_in, const int* in_sizes, int n_in,
                              void* d_out, int out_size, void* d_ws, size_t ws_size,
                              hipStream_t stream)
{
    const float* x    = (const float*)d_in[0];
    const float* Wq   = (const float*)d_in[1];
    const float* bq   = (const float*)d_in[2];
    const float* aq   = (const float*)d_in[3];
    const float* gq   = (const float*)d_in[4];
    const float* betq = (const float*)d_in[5];
    const float* Wk   = (const float*)d_in[6];
    const float* bk   = (const float*)d_in[7];
    const float* ak   = (const float*)d_in[8];
    const float* gk   = (const float*)d_in[9];
    const float* betk = (const float*)d_in[10];
    const float* Wv   = (const float*)d_in[11];
    const float* bv   = (const float*)d_in[12];
    const float* av   = (const float*)d_in[13];
    const float* gv   = (const float*)d_in[14];
    const float* betv = (const float*)d_in[15];
    const float* Wp   = (const float*)d_in[16];
    const float* bp   = (const float*)d_in[17];
    const float* ap   = (const float*)d_in[18];
    const float* gp   = (const float*)d_in[19];
    const float* betp = (const float*)d_in[20];

    short* Qb   = (short*)d_ws;
    short* Kb   = Qb   + (size_t)8 * 2048 * 256;
    short* Vrm  = Kb   + (size_t)8 * 2048 * 256;
    short* Vt   = Vrm  + (size_t)8 * 2048 * 1024;
    short* Obuf = Vt   + (size_t)8 * 2048 * 1024;
    short* Wbf  = Obuf + (size_t)8 * 2048 * 1024;
    short* Wpbf = Wbf  + 96 * 64;

    prep_kernel<<<40, 256, 0, stream>>>(Wq, Wk, Wv, Wp, Wbf, Wpbf);
    qkv_kernel<<<dim3(2048, 2), 256, 0, stream>>>(x, Wbf,
        bq, aq, gq, betq, bk, ak, gk, betk, bv, av, gv, betv, Qb, Kb, Vrm);
    vtrans_kernel<<<dim3(32, 16, 8), 256, 0, stream>>>(Vrm, Vt);
    attn_kernel<<<dim3(8, 16, 2), 512, 0, stream>>>(Qb, Kb, Vt, Obuf);
    oproj_kernel<<<dim3(2048, 2), 256, 0, stream>>>(Obuf, x, Wpbf,
        bp, ap, gp, betp, (float*)d_out);
}

// Round 13
// 239.952 us; speedup vs baseline: 1.2152x; 1.2152x over previous
//
#include <hip/hip_runtime.h>

#define EPS_ 1e-5f

typedef float f32x4 __attribute__((ext_vector_type(4)));
typedef short s16x8 __attribute__((ext_vector_type(8)));

static __device__ __forceinline__ short f2bf(float f) {
    unsigned u = __float_as_uint(f);
    unsigned r = (u + 0x7FFFu + ((u >> 16) & 1u)) >> 16;
    return (short)r;
}
static __device__ __forceinline__ float bf2f(short s) {
    return __uint_as_float(((unsigned)(unsigned short)s) << 16);
}

// async global->LDS, 16B per lane, wave-uniform LDS base
static __device__ __forceinline__ void gload16(const short* g, short* l) {
    __builtin_amdgcn_global_load_lds(
        (const __attribute__((address_space(1))) unsigned int*)g,
        (__attribute__((address_space(3))) unsigned int*)l, 16, 0, 0);
}

// ---------------------------------------------------------------------------
// Kernel 0: convert weight stacks to bf16 once.
// ---------------------------------------------------------------------------
__global__ __launch_bounds__(256) void prep_kernel(
    const float* __restrict__ Wq, const float* __restrict__ Wk,
    const float* __restrict__ Wv, const float* __restrict__ Wp,
    short* __restrict__ Wbf, short* __restrict__ Wpbf)
{
    int i = blockIdx.x * 256 + threadIdx.x;
    if (i < 6144) {
        float v = (i < 1024) ? Wq[i] : (i < 2048 ? Wk[i - 1024] : Wv[i - 2048]);
        Wbf[i] = f2bf(v);
    } else if (i < 6144 + 4096) {
        Wpbf[i - 6144] = f2bf(Wp[i - 6144]);
    }
}

// ---------------------------------------------------------------------------
// Kernel 1: QKV projection via MFMA + PReLU + LN(chan,freq), write bf16.
// ---------------------------------------------------------------------------
__global__ __launch_bounds__(256) void qkv_kernel(
    const float* __restrict__ x, const short* __restrict__ Wbf,
    const float* __restrict__ bq, const float* __restrict__ aq,
    const float* __restrict__ gq, const float* __restrict__ betq,
    const float* __restrict__ bk, const float* __restrict__ ak,
    const float* __restrict__ gk, const float* __restrict__ betk,
    const float* __restrict__ bv, const float* __restrict__ av,
    const float* __restrict__ gv, const float* __restrict__ betv,
    short* __restrict__ Qo, short* __restrict__ Ko, short* __restrict__ Vo)
{
    const int t = blockIdx.x;
    const int b = blockIdx.y;
    const int tid = threadIdx.x;
    const int wid = tid >> 6, lane = tid & 63;
    const int g = lane >> 4, c16 = lane & 15;
    const int f_ = tid & 63, cg = tid >> 6;

    __shared__ __align__(16) short wlds[96 * 64];
    __shared__ __align__(16) short xs[64 * 64];
    __shared__ float zs[96 * 64];
    __shared__ float stats[12][2];
    __shared__ float bias_l[96], alpha_l[96];

#pragma unroll
    for (int j = 0; j < 3; ++j) {
        int i8 = tid + 256 * j;
        int row = i8 >> 3, cb = i8 & 7;
        s16x8 v = *(const s16x8*)(Wbf + i8 * 8);
        *(s16x8*)&wlds[row * 64 + ((cb ^ (row & 7)) * 8)] = v;
    }
    if (tid < 96) {
        int row = tid; float bias, al;
        if (row < 16)      { bias = bq[row];      al = aq[row >> 2]; }
        else if (row < 32) { bias = bk[row - 16]; al = ak[(row - 16) >> 2]; }
        else               { bias = bv[row - 32]; al = av[(row - 32) >> 4]; }
        bias_l[row] = bias; alpha_l[row] = al;
    }
#pragma unroll
    for (int it = 0; it < 2; ++it) {
        int cb = cg + 4 * it, c0 = cb * 8;
        s16x8 v;
#pragma unroll
        for (int i = 0; i < 8; ++i)
            v[i] = f2bf(x[(((size_t)b * 64 + c0 + i) * 2048 + t) * 64 + f_]);
        *(s16x8*)&xs[f_ * 64 + ((cb ^ (f_ & 7)) * 8)] = v;
    }
    __syncthreads();

    const int f0 = wid * 16;
    s16x8 bfr[2];
#pragma unroll
    for (int kk = 0; kk < 2; ++kk)
        bfr[kk] = *(const s16x8*)&xs[(f0 + c16) * 64 + (((kk * 4 + g) ^ (c16 & 7)) * 8)];

    f32x4 acc[6];
#pragma unroll
    for (int rt = 0; rt < 6; ++rt) {
#pragma unroll
        for (int r = 0; r < 4; ++r) acc[rt][r] = 0.f;
#pragma unroll
        for (int kk = 0; kk < 2; ++kk) {
            s16x8 a = *(const s16x8*)&wlds[(rt * 16 + c16) * 64 + (((kk * 4 + g) ^ (c16 & 7)) * 8)];
            acc[rt] = __builtin_amdgcn_mfma_f32_16x16x32_bf16(a, bfr[kk], acc[rt], 0, 0, 0);
        }
    }

#pragma unroll
    for (int rt = 0; rt < 6; ++rt)
#pragma unroll
        for (int r = 0; r < 4; ++r) {
            int row = rt * 16 + g * 4 + r;
            float z = acc[rt][r] + bias_l[row];
            z = z >= 0.f ? z : alpha_l[row] * z;
            zs[row * 64 + f0 + c16] = z;
        }
    __syncthreads();

#pragma unroll
    for (int gi = 0; gi < 3; ++gi) {
        int grp = wid * 3 + gi;
        int base_row, n;
        if (grp < 4)      { base_row = grp * 4;             n = 256; }
        else if (grp < 8) { base_row = 16 + (grp - 4) * 4;  n = 256; }
        else              { base_row = 32 + (grp - 8) * 16; n = 1024; }
        int cnt = n >> 6;
        float s = 0.f, ss = 0.f;
        for (int i = 0; i < cnt; ++i) {
            float v = zs[(base_row + i) * 64 + lane];
            s += v; ss += v * v;
        }
#pragma unroll
        for (int msk = 32; msk >= 1; msk >>= 1) {
            s  += __shfl_xor(s, msk);
            ss += __shfl_xor(ss, msk);
        }
        if (lane == 0) {
            float mean = s / n;
            float var = ss / n - mean * mean;
            stats[grp][0] = mean;
            stats[grp][1] = rsqrtf(var + EPS_);
        }
    }
    __syncthreads();

#pragma unroll
    for (int j = 0; j < 24; ++j) {
        int row = cg + 4 * j;
        float zv = zs[row * 64 + f_];
        if (row < 16) {
            int grp = row >> 2;
            float val = (zv - stats[grp][0]) * stats[grp][1];
            val = val * gq[row * 64 + f_] + betq[row * 64 + f_];
            int h = row >> 2, o = row & 3;
            Qo[(((size_t)(h * 2 + b)) * 2048 + t) * 256 + o * 64 + f_] = f2bf(val);
        } else if (row < 32) {
            int rr = row - 16, grp = 4 + (rr >> 2);
            float val = (zv - stats[grp][0]) * stats[grp][1];
            val = val * gk[rr * 64 + f_] + betk[rr * 64 + f_];
            int h = rr >> 2, o = rr & 3;
            Ko[(((size_t)(h * 2 + b)) * 2048 + t) * 256 + o * 64 + f_] = f2bf(val);
        } else {
            int rr = row - 32, grp = 8 + (rr >> 4);
            float val = (zv - stats[grp][0]) * stats[grp][1];
            val = val * gv[rr * 64 + f_] + betv[rr * 64 + f_];
            int h = rr >> 4, ov = rr & 15;
            Vo[(((size_t)(h * 2 + b)) * 2048 + t) * 1024 + ov * 64 + f_] = f2bf(val);
        }
    }
}

// ---------------------------------------------------------------------------
// Kernel 2: V row-major [hb][t][d] -> V^T [hb][d][pi(t)] where pi relabels
// keys within each 32-aligned t-block so the in-register P from swapped
// QK^T feeds PV's A-operand with zero cross-lane movement.
// k' bits (b4 b3 b2 b1 b0) -> phys = b2*16 + b4*8 + b3*4 + b1b0.
// ---------------------------------------------------------------------------
__global__ __launch_bounds__(256) void vtrans_kernel(
    const short* __restrict__ Vrm, short* __restrict__ Vt)
{
    const int t0 = blockIdx.x * 64;
    const int d0 = blockIdx.y * 64;
    const int hb = blockIdx.z;
    const int tid = threadIdx.x;
    __shared__ __align__(16) short tile[64 * 72];

#pragma unroll
    for (int k = 0; k < 2; ++k) {
        int q = tid + 256 * k;
        int row = q >> 3, slot = q & 7;
        s16x8 v = *(const s16x8*)(Vrm + ((size_t)hb * 2048 + t0 + row) * 1024 + d0 + slot * 8);
        *(s16x8*)&tile[row * 72 + slot * 8] = v;
    }
    __syncthreads();
#pragma unroll
    for (int k = 0; k < 2; ++k) {
        int q = tid + 256 * k;
        int drow = q >> 3, tslot = q & 7;
        s16x8 v;
#pragma unroll
        for (int i = 0; i < 8; ++i) {
            int c = tslot * 8 + i;
            int cl = c & 31;
            int src = (c & 32) + ((cl >> 2) & 1) * 16 + ((cl >> 4) & 1) * 8
                    + ((cl >> 3) & 1) * 4 + (cl & 3);
            v[i] = tile[src * 72 + drow];
        }
        *(s16x8*)(Vt + ((size_t)hb * 1024 + d0 + drow) * 2048 + t0 + tslot * 8) = v;
    }
}

// ---------------------------------------------------------------------------
// Kernel 3: flash attention — DMA-fed, P shared via LDS at b128 granularity.
// Grid (8 hb, 16 qt, 2 dh) = 256 blocks, 512 thr (8 waves). QBLK=128,
// KBLK=32, 64 k-tiles.
// QK^T (swapped, wave owns 16 q-rows): A=K from k_lds (16 reads, 16 MFMA),
//   softmax in-register (8 exp + 2 shfl), pa packed via pi -> ONE
//   ds_write_b128 to p_lds (pa is already PV A-operand layout).
// PV (wave owns 64-d slice of the 512 half): 4 V reads (each reused across
//   8 q-subtiles) + 8 P reads -> 32 MFMA. V reuse restored: per CU per tile
//   232 ds_reads for 384 MFMA (r11: 384 reads).
// Pipeline, 1 barrier/tile: K staged t+2 ahead; V and P double-buffered;
//   tile t body = { STAGE_K(t+2) | STAGE_V(t+1) | QKT(t+1)->p[(t+1)&1] |
//   PV(t) from p[t&1],v[t&1] | barrier }.
// LDS: K 2x16K + V 2x32K + P 2x8K = 112.5 KB. Regs ~110 VGPR + 128 AGPR.
// ---------------------------------------------------------------------------
__global__ __launch_bounds__(512, 2) void attn_kernel(
    const short* __restrict__ Qg, const short* __restrict__ Kg,
    const short* __restrict__ Vt, short* __restrict__ Ob)
{
    const int hb = blockIdx.x;
    const int qt = blockIdx.y;     // 0..15
    const int dh = blockIdx.z;     // 0..1
    const int t0 = qt * 128;
    const int tid = threadIdx.x;
    const int lane = tid & 63;
    const int wid = tid >> 6;      // q-stripe (QK^T) / d-slice (PV)
    const int g = lane >> 4, c16 = lane & 15;

    __shared__ __align__(16) short k_lds[2][32 * 256];   // 2x16 KB
    __shared__ __align__(16) short v_lds[2][512 * 32];   // 2x32 KB
    __shared__ __align__(16) short p_lds[2][8][512];     // 2x8 KB
    __shared__ float l_sh[128];

    const size_t kgbase = (size_t)hb * 2048 * 256;
    const size_t vgbase = ((size_t)hb * 1024 + dh * 512) * 2048;
    const int dsl = wid * 64;      // this wave's d-slice within the 512 half

    // Q B-fragments for q-stripe wid (16 rows x 256 d), persistent
    const size_t qrow = (size_t)hb * 2048 + t0 + wid * 16 + c16;
    s16x8 qf[8];
#pragma unroll
    for (int kf = 0; kf < 8; ++kf)
        qf[kf] = *(const s16x8*)(Qg + qrow * 256 + kf * 32 + g * 8);

    f32x4 oacc[32];                // [qs 0..7][dt 0..3]
#pragma unroll
    for (int i = 0; i < 32; ++i)
#pragma unroll
        for (int r = 0; r < 4; ++r) oacc[i][r] = 0.f;

    float l_r = 0.f;               // softmax denom for q = wid*16 + c16

#define STAGE_K(buf, kt) do {                                                  \
    _Pragma("unroll")                                                          \
    for (int j_ = 0; j_ < 2; ++j_) {                                           \
        int c_ = tid + 512 * j_;                                               \
        int row_ = c_ >> 5, sp_ = c_ & 31;                                     \
        int sl_ = sp_ ^ (row_ & 7);                                            \
        gload16(Kg + kgbase + (size_t)((kt) * 32 + row_) * 256 + sl_ * 8,      \
                &k_lds[buf][c_ * 8]);                                          \
    }                                                                          \
} while (0)

#define STAGE_V(buf, kt) do {                                                  \
    _Pragma("unroll")                                                          \
    for (int j_ = 0; j_ < 4; ++j_) {                                           \
        int c_ = tid + 512 * j_;                                               \
        int row_ = c_ >> 2, sp_ = c_ & 3;                                      \
        int sl_ = sp_ ^ ((row_ >> 1) & 3);                                     \
        gload16(Vt + vgbase + (size_t)row_ * 2048 + (kt) * 32 + sl_ * 8,       \
                &v_lds[buf][c_ * 8]);                                          \
    }                                                                          \
} while (0)

    // QK^T for tile nt (swapped): lane ends with P[key][q=c16] for 32 keys,
    // packed via pi into pa (PV A-operand layout), one b128 write to p_lds.
#define QKT_PHASE(nt) do {                                                     \
    f32x4 sf0, sf1;                                                            \
    _Pragma("unroll")                                                          \
    for (int r = 0; r < 4; ++r) { sf0[r] = 0.f; sf1[r] = 0.f; }                \
    __builtin_amdgcn_s_setprio(1);                                             \
    _Pragma("unroll")                                                          \
    for (int kf = 0; kf < 8; ++kf) {                                           \
        int sl_ = ((kf * 4 + g) ^ (c16 & 7)) * 8;                              \
        s16x8 ka0 = *(const s16x8*)&k_lds[(nt) & 1][c16 * 256 + sl_];          \
        sf0 = __builtin_amdgcn_mfma_f32_16x16x32_bf16(ka0, qf[kf], sf0, 0, 0, 0); \
        s16x8 ka1 = *(const s16x8*)&k_lds[(nt) & 1][(16 + c16) * 256 + sl_];   \
        sf1 = __builtin_amdgcn_mfma_f32_16x16x32_bf16(ka1, qf[kf], sf1, 0, 0, 0); \
    }                                                                          \
    __builtin_amdgcn_s_setprio(0);                                             \
    float rs = 0.f;                                                            \
    _Pragma("unroll")                                                          \
    for (int r = 0; r < 4; ++r) {                                              \
        float p0 = __expf(sf0[r] * 0.0625f);                                   \
        float p1 = __expf(sf1[r] * 0.0625f);                                   \
        sf0[r] = p0; sf1[r] = p1;                                              \
        rs += p0 + p1;                                                         \
    }                                                                          \
    rs += __shfl_xor(rs, 16);                                                  \
    rs += __shfl_xor(rs, 32);                                                  \
    l_r += rs;                                                                 \
    s16x8 pa;                                                                  \
    _Pragma("unroll")                                                          \
    for (int e = 0; e < 8; ++e)                                                \
        pa[e] = f2bf((e & 4) ? sf1[e & 3] : sf0[e & 3]);                       \
    *(s16x8*)&p_lds[(nt) & 1][wid][lane * 8] = pa;                             \
} while (0)

    // prologue
    STAGE_K(0, 0);
    __syncthreads();               // K0 ready
    STAGE_K(1, 1);
    STAGE_V(0, 0);
    QKT_PHASE(0);                  // reads k[0], writes p[0]
    __syncthreads();               // K1+V0 drained, p[0] visible

    for (int t = 0; t < 64; ++t) {
        const int buf = t & 1;

        if (t < 62) STAGE_K(buf, t + 2);       // k[(t+2)&1] == k[buf]
        if (t < 63) STAGE_V(buf ^ 1, t + 1);
        if (t < 63) QKT_PHASE(t + 1);          // k[(t+1)&1], writes p[buf^1]

        // PV(t): 4 V B-frags (reused across 8 q-subtiles) + 8 P A-frags
        s16x8 vb[4];
#pragma unroll
        for (int dt = 0; dt < 4; ++dt) {
            int rowv = dsl + dt * 16 + c16;
            vb[dt] = *(const s16x8*)&v_lds[buf][rowv * 32 + ((g ^ ((c16 >> 1) & 3)) * 8)];
        }
        __builtin_amdgcn_s_setprio(1);
#pragma unroll
        for (int qs = 0; qs < 8; ++qs) {
            s16x8 pa = *(const s16x8*)&p_lds[buf][qs][lane * 8];
#pragma unroll
            for (int dt = 0; dt < 4; ++dt)
                oacc[qs * 4 + dt] = __builtin_amdgcn_mfma_f32_16x16x32_bf16(
                    pa, vb[dt], oacc[qs * 4 + dt], 0, 0, 0);
        }
        __builtin_amdgcn_s_setprio(0);

        if (t < 63) __syncthreads();   // DMA drained; p/v/k parity safe
    }

#undef STAGE_K
#undef STAGE_V
#undef QKT_PHASE

    // share softmax denominators (wave wid owns q-rows wid*16 + 0..15)
    __syncthreads();
    if (lane < 16) l_sh[wid * 16 + lane] = l_r;
    __syncthreads();

    // epilogue: O /= l, write bf16 in [b][h*16+ov][t][f] layout
    const int h = hb >> 1, b = hb & 1;
#pragma unroll
    for (int qs = 0; qs < 8; ++qs) {
        float li[4];
#pragma unroll
        for (int r = 0; r < 4; ++r)
            li[r] = 1.f / l_sh[qs * 16 + g * 4 + r];
#pragma unroll
        for (int dt = 0; dt < 4; ++dt) {
            int vcol = dh * 512 + dsl + dt * 16 + c16;
            int cout = h * 16 + (vcol >> 6), ff = vcol & 63;
#pragma unroll
            for (int r = 0; r < 4; ++r) {
                int trow = t0 + qs * 16 + g * 4 + r;
                Ob[(((size_t)b * 64 + cout) * 2048 + trow) * 64 + ff] =
                    f2bf(oacc[qs * 4 + dt][r] * li[r]);
            }
        }
    }
}

// ---------------------------------------------------------------------------
// Kernel 4: output projection via MFMA + PReLU + LN(C,F) + residual
// ---------------------------------------------------------------------------
__global__ __launch_bounds__(256) void oproj_kernel(
    const short* __restrict__ Ob, const float* __restrict__ x,
    const short* __restrict__ Wpbf,
    const float* __restrict__ bp, const float* __restrict__ ap,
    const float* __restrict__ gp, const float* __restrict__ betp,
    float* __restrict__ out)
{
    const int t = blockIdx.x;
    const int b = blockIdx.y;
    const int tid = threadIdx.x;
    const int wid = tid >> 6, lane = tid & 63;
    const int g = lane >> 4, c16 = lane & 15;
    const int f_ = tid & 63, cg = tid >> 6;

    __shared__ __align__(16) short wp[64 * 64];
    __shared__ __align__(16) short os[64 * 64];
    __shared__ float zs[64 * 64];
    __shared__ float red[4][2];

#pragma unroll
    for (int j = 0; j < 2; ++j) {
        int i8 = tid + 256 * j;
        int row = i8 >> 3, cb = i8 & 7;
        s16x8 v = *(const s16x8*)(Wpbf + i8 * 8);
        *(s16x8*)&wp[row * 64 + ((cb ^ (row & 7)) * 8)] = v;
    }
#pragma unroll
    for (int it = 0; it < 2; ++it) {
        int cb = cg + 4 * it, c0 = cb * 8;
        s16x8 v;
#pragma unroll
        for (int i = 0; i < 8; ++i)
            v[i] = Ob[(((size_t)b * 64 + c0 + i) * 2048 + t) * 64 + f_];
        *(s16x8*)&os[f_ * 64 + ((cb ^ (f_ & 7)) * 8)] = v;
    }
    __syncthreads();

    const int f0 = wid * 16;
    s16x8 bfr[2];
#pragma unroll
    for (int kk = 0; kk < 2; ++kk)
        bfr[kk] = *(const s16x8*)&os[(f0 + c16) * 64 + (((kk * 4 + g) ^ (c16 & 7)) * 8)];

    const float ap0 = ap[0];
    f32x4 acc[4];
#pragma unroll
    for (int rt = 0; rt < 4; ++rt) {
#pragma unroll
        for (int r = 0; r < 4; ++r) acc[rt][r] = 0.f;
#pragma unroll
        for (int kk = 0; kk < 2; ++kk) {
            s16x8 a = *(const s16x8*)&wp[(rt * 16 + c16) * 64 + (((kk * 4 + g) ^ (c16 & 7)) * 8)];
            acc[rt] = __builtin_amdgcn_mfma_f32_16x16x32_bf16(a, bfr[kk], acc[rt], 0, 0, 0);
        }
    }

#pragma unroll
    for (int rt = 0; rt < 4; ++rt)
#pragma unroll
        for (int r = 0; r < 4; ++r) {
            int row = rt * 16 + g * 4 + r;
            float z = acc[rt][r] + bp[row];
            z = z >= 0.f ? z : ap0 * z;
            zs[row * 64 + f0 + c16] = z;
        }
    __syncthreads();

    float s = 0.f, ss = 0.f;
#pragma unroll
    for (int j = 0; j < 16; ++j) {
        float v = zs[(cg + 4 * j) * 64 + f_];
        s += v; ss += v * v;
    }
#pragma unroll
    for (int msk = 32; msk >= 1; msk >>= 1) {
        s  += __shfl_xor(s, msk);
        ss += __shfl_xor(ss, msk);
    }
    if (lane == 0) { red[wid][0] = s; red[wid][1] = ss; }
    __syncthreads();
    float ts  = red[0][0] + red[1][0] + red[2][0] + red[3][0];
    float tss = red[0][1] + red[1][1] + red[2][1] + red[3][1];
    float mean = ts * (1.f / 4096.f);
    float rstd = rsqrtf(tss * (1.f / 4096.f) - mean * mean + EPS_);

#pragma unroll
    for (int j = 0; j < 16; ++j) {
        int row = cg + 4 * j;
        size_t idx = (((size_t)b * 64 + row) * 2048 + t) * 64 + f_;
        out[idx] = (zs[row * 64 + f_] - mean) * rstd * gp[row * 64 + f_]
                 + betp[row * 64 + f_] + x[idx];
    }
}

// ---------------------------------------------------------------------------
extern "C" void kernel_launch(void* const* d_in, const int* in_sizes, int n_in,
                              void* d_out, int out_size, void* d_ws, size_t ws_size,
                              hipStream_t stream)
{
    const float* x    = (const float*)d_in[0];
    const float* Wq   = (const float*)d_in[1];
    const float* bq   = (const float*)d_in[2];
    const float* aq   = (const float*)d_in[3];
    const float* gq   = (const float*)d_in[4];
    const float* betq = (const float*)d_in[5];
    const float* Wk   = (const float*)d_in[6];
    const float* bk   = (const float*)d_in[7];
    const float* ak   = (const float*)d_in[8];
    const float* gk   = (const float*)d_in[9];
    const float* betk = (const float*)d_in[10];
    const float* Wv   = (const float*)d_in[11];
    const float* bv   = (const float*)d_in[12];
    const float* av   = (const float*)d_in[13];
    const float* gv   = (const float*)d_in[14];
    const float* betv = (const float*)d_in[15];
    const float* Wp   = (const float*)d_in[16];
    const float* bp   = (const float*)d_in[17];
    const float* ap   = (const float*)d_in[18];
    const float* gp   = (const float*)d_in[19];
    const float* betp = (const float*)d_in[20];

    short* Qb   = (short*)d_ws;
    short* Kb   = Qb   + (size_t)8 * 2048 * 256;
    short* Vrm  = Kb   + (size_t)8 * 2048 * 256;
    short* Vt   = Vrm  + (size_t)8 * 2048 * 1024;
    short* Obuf = Vt   + (size_t)8 * 2048 * 1024;
    short* Wbf  = Obuf + (size_t)8 * 2048 * 1024;
    short* Wpbf = Wbf  + 96 * 64;

    prep_kernel<<<40, 256, 0, stream>>>(Wq, Wk, Wv, Wp, Wbf, Wpbf);
    qkv_kernel<<<dim3(2048, 2), 256, 0, stream>>>(x, Wbf,
        bq, aq, gq, betq, bk, ak, gk, betk, bv, av, gv, betv, Qb, Kb, Vrm);
    vtrans_kernel<<<dim3(32, 16, 8), 256, 0, stream>>>(Vrm, Vt);
    attn_kernel<<<dim3(8, 16, 2), 512, 0, stream>>>(Qb, Kb, Vt, Obuf);
    oproj_kernel<<<dim3(2048, 2), 256, 0, stream>>>(Obuf, x, Wpbf,
        bp, ap, gp, betp, (float*)d_out);
}